// Round 1
// baseline (3000.183 us; speedup 1.0000x reference)
//
#include <hip/hip_runtime.h>

typedef short bf16x8 __attribute__((ext_vector_type(8)));
typedef float f32x4 __attribute__((ext_vector_type(4)));

#define DEV __device__ __forceinline__

constexpr int SEQ = 2048;
constexpr int HID = 4096;
constexpr int NH  = 32;
constexpr int NKV = 8;
constexpr int DH  = 128;
constexpr int FF  = 14336;

DEV unsigned short f2bf(float f) {
  union { float f; unsigned u; } x; x.f = f;
  unsigned r = x.u + 0x7fffu + ((x.u >> 16) & 1u);
  return (unsigned short)(r >> 16);
}
DEV float bf2f(unsigned short u) {
  union { unsigned u; float f; } x; x.u = ((unsigned)u) << 16; return x.f;
}
DEV void gload16(const void* g, void* l) {
  __builtin_amdgcn_global_load_lds(
      (const __attribute__((address_space(1))) unsigned*)g,
      (__attribute__((address_space(3))) unsigned*)l, 16, 0, 0);
}

// ---------------------------------------------------------------- RMSNorm
__global__ __launch_bounds__(256) void rmsnorm_kernel(
    const float* __restrict__ x, const float* __restrict__ w,
    unsigned short* __restrict__ out) {
  const int row = blockIdx.x;
  const int tid = threadIdx.x;
  const float* xr = x + (size_t)row * HID;
  float4 v[4];
  float ss = 0.f;
#pragma unroll
  for (int i = 0; i < 4; ++i) {
    v[i] = *(const float4*)(xr + i * 1024 + tid * 4);
    ss += v[i].x * v[i].x + v[i].y * v[i].y + v[i].z * v[i].z + v[i].w * v[i].w;
  }
#pragma unroll
  for (int m = 1; m < 64; m <<= 1) ss += __shfl_xor(ss, m);
  __shared__ float red[4];
  if ((tid & 63) == 0) red[tid >> 6] = ss;
  __syncthreads();
  float tot = red[0] + red[1] + red[2] + red[3];
  float rms = rsqrtf(tot / (float)HID + 1e-5f);
  unsigned short* orow = out + (size_t)row * HID;
#pragma unroll
  for (int i = 0; i < 4; ++i) {
    int base = i * 1024 + tid * 4;
    ushort4 o;
    o.x = f2bf(v[i].x * rms * w[base + 0]);
    o.y = f2bf(v[i].y * rms * w[base + 1]);
    o.z = f2bf(v[i].z * rms * w[base + 2]);
    o.w = f2bf(v[i].w * rms * w[base + 3]);
    *(ushort4*)(orow + base) = o;
  }
}

// ---------------------------------------------------------------- RoPE (in-place)
template <int NHEADS>
__global__ __launch_bounds__(256) void rope_kernel(unsigned short* __restrict__ x) {
  const int gid = blockIdx.x * 256 + threadIdx.x;
  const int i = gid & 63;
  const int t = gid >> 6;        // (s, head) flat index
  const int s = t / NHEADS;      // position (ids are arange)
  // inv_freq = 1e9^(-2i/128) = exp2(-i/64 * log2(1e9))
  float ang = (float)s * exp2f((float)i * (-29.897352853986263f / 64.f));
  float sn, cs;
  sincosf(ang, &sn, &cs);
  size_t base = (size_t)t * DH + i;
  float x1 = bf2f(x[base]);
  float x2 = bf2f(x[base + 64]);
  x[base]      = f2bf(x1 * cs - x2 * sn);
  x[base + 64] = f2bf(x2 * cs + x1 * sn);
}

// ---------------------------------------------------------------- SiLU(g)*u
__global__ __launch_bounds__(256) void silu_mul_kernel(
    const unsigned short* __restrict__ g, const unsigned short* __restrict__ u,
    unsigned short* __restrict__ out) {
  const size_t idx = ((size_t)blockIdx.x * 256 + threadIdx.x) * 4;
  ushort4 gv = *(const ushort4*)(g + idx);
  ushort4 uv = *(const ushort4*)(u + idx);
  float gf[4] = {bf2f(gv.x), bf2f(gv.y), bf2f(gv.z), bf2f(gv.w)};
  float uf[4] = {bf2f(uv.x), bf2f(uv.y), bf2f(uv.z), bf2f(uv.w)};
  ushort4 o;
  unsigned short* op = (unsigned short*)&o;
#pragma unroll
  for (int j = 0; j < 4; ++j) {
    float sl = gf[j] / (1.f + __expf(-gf[j]));
    op[j] = f2bf(sl * uf[j]);
  }
  *(ushort4*)(out + idx) = o;
}

// ---------------------------------------------------------------- GEMM
// C[M,N] = A[M,K](bf16,row) @ B[K,N](fp32,row)
// EPI=0: C bf16.  EPI=1: C fp32 = acc + res[M,N](fp32).
// 128x128 tile, BK=64, 4 waves (2x2 of 64x64), mfma 16x16x32 bf16.
template <int EPI>
__global__ __launch_bounds__(256, 2) void gemm_kernel(
    const unsigned short* __restrict__ A, const float* __restrict__ B,
    void* __restrict__ Cv, const float* __restrict__ res, int N, int K) {
  __shared__ __align__(128) char sm[2 * 128 * 64 * 2];  // 16KB A + 16KB B
  char* sA = sm;
  char* sB = sm + 128 * 64 * 2;
  const int tid  = threadIdx.x;
  const int lane = tid & 63;
  const int wv   = tid >> 6;
  const int m0 = blockIdx.x * 128;
  const int n0 = blockIdx.y * 128;
  const int wm = (wv >> 1) * 64;
  const int wn = (wv & 1) * 64;

  f32x4 acc[4][4] = {};

  // A staging geometry: lds linear [row(128)][kbyte(128)], XOR-swizzled source
  const int oA   = wv * 1024 + lane * 16;
  const int rowA = oA >> 7;      // + 32*i
  const int cA   = oA & 127;
  // B staging geometry: 2 k x 4 n fp32 per thread per sub-iter
  const int nB  = (tid & 31) * 4;
  const int k2B = (tid >> 5) * 2;  // + 16*i

  for (int kt = 0; kt < K; kt += 64) {
    __syncthreads();
    // ---- stage A (bf16) via global_load_lds, pre-swizzled source
#pragma unroll
    for (int i = 0; i < 4; ++i) {
      int row = rowA + 32 * i;
      const char* gp = (const char*)A + ((size_t)(m0 + row) * K + kt) * 2 +
                       (cA ^ ((row & 7) << 4));
      gload16(gp, sA + i * 4096 + wv * 1024);
    }
    // ---- stage B (fp32 -> bf16, transpose to [n][k], swizzled)
#pragma unroll
    for (int i = 0; i < 4; ++i) {
      int k2 = k2B + 16 * i;
      const float* g0 = B + (size_t)(kt + k2) * N + (n0 + nB);
      float4 r0 = *(const float4*)g0;
      float4 r1 = *(const float4*)(g0 + N);
      unsigned pk[4];
      pk[0] = (unsigned)f2bf(r0.x) | ((unsigned)f2bf(r1.x) << 16);
      pk[1] = (unsigned)f2bf(r0.y) | ((unsigned)f2bf(r1.y) << 16);
      pk[2] = (unsigned)f2bf(r0.z) | ((unsigned)f2bf(r1.z) << 16);
      pk[3] = (unsigned)f2bf(r0.w) | ((unsigned)f2bf(r1.w) << 16);
#pragma unroll
      for (int j = 0; j < 4; ++j) {
        int n = nB + j;
        *(unsigned*)(sB + ((n * 128 + k2 * 2) ^ ((n & 7) << 4))) = pk[j];
      }
    }
    __syncthreads();
    // ---- compute: 2 k-steps x (4 mi x 4 ni) MFMAs
#pragma unroll
    for (int kk = 0; kk < 2; ++kk) {
      const int kb = ((lane >> 4) * 16) + kk * 64;
      bf16x8 af[4], bfr[4];
#pragma unroll
      for (int mi = 0; mi < 4; ++mi) {
        int row = wm + mi * 16 + (lane & 15);
        af[mi] = *(const bf16x8*)(sA + ((row * 128 + kb) ^ ((row & 7) << 4)));
      }
#pragma unroll
      for (int ni = 0; ni < 4; ++ni) {
        int col = wn + ni * 16 + (lane & 15);
        bfr[ni] = *(const bf16x8*)(sB + ((col * 128 + kb) ^ ((col & 7) << 4)));
      }
#pragma unroll
      for (int mi = 0; mi < 4; ++mi)
#pragma unroll
        for (int ni = 0; ni < 4; ++ni)
          acc[mi][ni] = __builtin_amdgcn_mfma_f32_16x16x32_bf16(
              af[mi], bfr[ni], acc[mi][ni], 0, 0, 0);
    }
  }

  const int rbase = (lane >> 4) * 4;
  const int cbase = lane & 15;
#pragma unroll
  for (int mi = 0; mi < 4; ++mi)
#pragma unroll
    for (int ni = 0; ni < 4; ++ni)
#pragma unroll
      for (int r = 0; r < 4; ++r) {
        size_t row = (size_t)(m0 + wm + mi * 16 + rbase + r);
        size_t col = (size_t)(n0 + wn + ni * 16 + cbase);
        float vv = acc[mi][ni][r];
        if (EPI == 0) {
          ((unsigned short*)Cv)[row * N + col] = f2bf(vv);
        } else {
          ((float*)Cv)[row * N + col] = vv + res[row * N + col];
        }
      }
}

// ---------------------------------------------------------------- Flash attention
// grid (SEQ/64, NH). Block: 4 waves, each owns 16 q-rows. KV tiles of 64.
__global__ __launch_bounds__(256, 2) void attn_kernel(
    const unsigned short* __restrict__ Q, const unsigned short* __restrict__ Kb,
    const unsigned short* __restrict__ Vb, unsigned short* __restrict__ Ob) {
  __shared__ __align__(128) char sm[16384 * 3 + 8192];  // Q,K,V^T,P
  char* sQ = sm;
  char* sK = sm + 16384;
  char* sV = sm + 32768;
  char* sP = sm + 49152;
  const int tid  = threadIdx.x;
  const int lane = tid & 63;
  const int wv   = tid >> 6;
  const int qb0  = blockIdx.x * 64;
  const int h    = blockIdx.y;
  const int hkv  = h >> 2;  // G = 4
  const int rbase = (lane >> 4) * 4;
  const int cbase = lane & 15;

  // ---- stage Q (64 x 128 bf16, 256B rows, swizzle (row&15)<<4)
  const int oQ   = wv * 1024 + lane * 16;
  const int rowQ = oQ >> 8;  // + 16*i
  const int cQ   = oQ & 255;
#pragma unroll
  for (int i = 0; i < 4; ++i) {
    int row = rowQ + 16 * i;
    const char* gp = (const char*)Q +
                     ((size_t)(qb0 + row) * (NH * DH) + h * DH) * 2 +
                     (cQ ^ ((row & 15) << 4));
    gload16(gp, sQ + i * 4096 + wv * 1024);
  }

  f32x4 oacc[8] = {};
  float m_r[4] = {-1e30f, -1e30f, -1e30f, -1e30f};
  float l_r[4] = {0.f, 0.f, 0.f, 0.f};

  const int d4   = (tid & 31) * 4;
  const int kv2b = (tid >> 5) * 2;
  const int ntiles = blockIdx.x + 1;

  for (int t = 0; t < ntiles; ++t) {
    const int kt0 = t * 64;
    __syncthreads();
    // ---- stage K tile
#pragma unroll
    for (int i = 0; i < 4; ++i) {
      int row = rowQ + 16 * i;
      const char* gp = (const char*)Kb +
                       ((size_t)(kt0 + row) * (NKV * DH) + hkv * DH) * 2 +
                       (cQ ^ ((row & 15) << 4));
      gload16(gp, sK + i * 4096 + wv * 1024);
    }
    // ---- stage V^T tile: [d(128)][kv(64)] bf16, 128B rows
#pragma unroll
    for (int i = 0; i < 4; ++i) {
      int kv2 = kv2b + 16 * i;
      const unsigned short* g0 =
          Vb + (size_t)(kt0 + kv2) * (NKV * DH) + hkv * DH + d4;
      ushort4 r0 = *(const ushort4*)g0;
      ushort4 r1 = *(const ushort4*)(g0 + NKV * DH);
      unsigned short a0[4] = {r0.x, r0.y, r0.z, r0.w};
      unsigned short a1[4] = {r1.x, r1.y, r1.z, r1.w};
#pragma unroll
      for (int j = 0; j < 4; ++j) {
        int dd = d4 + j;
        *(unsigned*)(sV + ((dd * 128 + kv2 * 2) ^ ((dd & 7) << 4))) =
            (unsigned)a0[j] | ((unsigned)a1[j] << 16);
      }
    }
    __syncthreads();

    // ---- S = Q K^T (wave: 16 q x 64 kv)
    f32x4 sacc[4] = {};
#pragma unroll
    for (int kk = 0; kk < 4; ++kk) {
      int kb = (lane >> 4) * 16 + kk * 64;
      int qrow = wv * 16 + (lane & 15);
      bf16x8 aq =
          *(const bf16x8*)(sQ + ((qrow * 256 + kb) ^ ((qrow & 15) << 4)));
#pragma unroll
      for (int ni = 0; ni < 4; ++ni) {
        int krow = ni * 16 + (lane & 15);
        bf16x8 bk =
            *(const bf16x8*)(sK + ((krow * 256 + kb) ^ ((krow & 15) << 4)));
        sacc[ni] =
            __builtin_amdgcn_mfma_f32_16x16x32_bf16(aq, bk, sacc[ni], 0, 0, 0);
      }
    }

    // ---- online softmax
    const float scale = 0.08838834764831845f;  // 1/sqrt(128)
#pragma unroll
    for (int r = 0; r < 4; ++r) {
      int qg = qb0 + wv * 16 + rbase + r;
      float mx = -1e30f;
#pragma unroll
      for (int ni = 0; ni < 4; ++ni) {
        int cg = kt0 + ni * 16 + cbase;
        float sv = sacc[ni][r] * scale;
        sv = (cg <= qg) ? sv : -1e30f;
        sacc[ni][r] = sv;
        mx = fmaxf(mx, sv);
      }
      mx = fmaxf(mx, __shfl_xor(mx, 1));
      mx = fmaxf(mx, __shfl_xor(mx, 2));
      mx = fmaxf(mx, __shfl_xor(mx, 4));
      mx = fmaxf(mx, __shfl_xor(mx, 8));
      float mnew = fmaxf(m_r[r], mx);
      float sf = __expf(m_r[r] - mnew);
      m_r[r] = mnew;
      float rsum = 0.f;
#pragma unroll
      for (int ni = 0; ni < 4; ++ni) {
        float pv = __expf(sacc[ni][r] - mnew);
        sacc[ni][r] = pv;
        rsum += pv;
      }
      rsum += __shfl_xor(rsum, 1);
      rsum += __shfl_xor(rsum, 2);
      rsum += __shfl_xor(rsum, 4);
      rsum += __shfl_xor(rsum, 8);
      l_r[r] = l_r[r] * sf + rsum;
#pragma unroll
      for (int nt = 0; nt < 8; ++nt) oacc[nt][r] *= sf;
    }

    // ---- P -> LDS (per-wave [16][64] bf16 region), then PV
    char* pw = sP + wv * 2048;
#pragma unroll
    for (int ni = 0; ni < 4; ++ni)
#pragma unroll
      for (int r = 0; r < 4; ++r) {
        int row = rbase + r;
        int cb2 = (ni * 16 + cbase) * 2;
        *(unsigned short*)(pw + ((row * 128 + cb2) ^ ((row & 7) << 4))) =
            f2bf(sacc[ni][r]);
      }
    asm volatile("s_waitcnt lgkmcnt(0)" ::: "memory");

#pragma unroll
    for (int kk = 0; kk < 2; ++kk) {
      int kb = (lane >> 4) * 16 + kk * 64;
      int prow = lane & 15;
      bf16x8 ap =
          *(const bf16x8*)(pw + ((prow * 128 + kb) ^ ((prow & 7) << 4)));
#pragma unroll
      for (int nt = 0; nt < 8; ++nt) {
        int vrow = nt * 16 + (lane & 15);
        bf16x8 bv =
            *(const bf16x8*)(sV + ((vrow * 128 + kb) ^ ((vrow & 7) << 4)));
        oacc[nt] =
            __builtin_amdgcn_mfma_f32_16x16x32_bf16(ap, bv, oacc[nt], 0, 0, 0);
      }
    }
  }

  // ---- epilogue: O / l
#pragma unroll
  for (int nt = 0; nt < 8; ++nt)
#pragma unroll
    for (int r = 0; r < 4; ++r) {
      size_t row = (size_t)(qb0 + wv * 16 + rbase + r);
      int col = nt * 16 + cbase;
      Ob[row * (NH * DH) + h * DH + col] = f2bf(oacc[nt][r] / l_r[r]);
    }
}

// ---------------------------------------------------------------- host
extern "C" void kernel_launch(void* const* d_in, const int* in_sizes, int n_in,
                              void* d_out, int out_size, void* d_ws,
                              size_t ws_size, hipStream_t stream) {
  const float* hs  = (const float*)d_in[0];
  const float* wq  = (const float*)d_in[1];
  const float* wk  = (const float*)d_in[2];
  const float* wvp = (const float*)d_in[3];
  const float* wo  = (const float*)d_in[4];
  const float* wg  = (const float*)d_in[5];
  const float* wu  = (const float*)d_in[6];
  const float* wd  = (const float*)d_in[7];
  const float* ln1 = (const float*)d_in[8];
  const float* ln2 = (const float*)d_in[9];

  char* p = (char*)d_ws;
  size_t need = 0;
  auto alloc = [&](size_t bytes) {
    char* r = p + need;
    need += (bytes + 255) & ~(size_t)255;
    return r;
  };
  unsigned short* xn   = (unsigned short*)alloc((size_t)SEQ * HID * 2);
  unsigned short* qb   = (unsigned short*)alloc((size_t)SEQ * NH * DH * 2);
  unsigned short* kb   = (unsigned short*)alloc((size_t)SEQ * NKV * DH * 2);
  unsigned short* vb   = (unsigned short*)alloc((size_t)SEQ * NKV * DH * 2);
  unsigned short* ab   = (unsigned short*)alloc((size_t)SEQ * NH * DH * 2);
  float*          h2   = (float*)alloc((size_t)SEQ * HID * 4);
  unsigned short* xn2  = (unsigned short*)alloc((size_t)SEQ * HID * 2);
  unsigned short* gbuf = (unsigned short*)alloc((size_t)SEQ * FF * 2);
  unsigned short* ubuf = (unsigned short*)alloc((size_t)SEQ * FF * 2);
  if (need > ws_size) return;  // workspace too small: fail visibly, no corruption

  // 1) rmsnorm1
  rmsnorm_kernel<<<SEQ, 256, 0, stream>>>(hs, ln1, xn);
  // 2) q/k/v projections
  gemm_kernel<0><<<dim3(SEQ / 128, (NH * DH) / 128), 256, 0, stream>>>(
      xn, wq, qb, nullptr, NH * DH, HID);
  gemm_kernel<0><<<dim3(SEQ / 128, (NKV * DH) / 128), 256, 0, stream>>>(
      xn, wk, kb, nullptr, NKV * DH, HID);
  gemm_kernel<0><<<dim3(SEQ / 128, (NKV * DH) / 128), 256, 0, stream>>>(
      xn, wvp, vb, nullptr, NKV * DH, HID);
  // 3) RoPE (in place)
  rope_kernel<NH><<<(SEQ * NH * 64) / 256, 256, 0, stream>>>(qb);
  rope_kernel<NKV><<<(SEQ * NKV * 64) / 256, 256, 0, stream>>>(kb);
  // 4) attention
  attn_kernel<<<dim3(SEQ / 64, NH), 256, 0, stream>>>(qb, kb, vb, ab);
  // 5) o-proj + residual -> h2 (fp32)
  gemm_kernel<1><<<dim3(SEQ / 128, HID / 128), 256, 0, stream>>>(
      ab, wo, h2, hs, HID, NH * DH);
  // 6) rmsnorm2
  rmsnorm_kernel<<<SEQ, 256, 0, stream>>>(h2, ln2, xn2);
  // 7) gate / up
  gemm_kernel<0><<<dim3(SEQ / 128, FF / 128), 256, 0, stream>>>(
      xn2, wg, gbuf, nullptr, FF, HID);
  gemm_kernel<0><<<dim3(SEQ / 128, FF / 128), 256, 0, stream>>>(
      xn2, wu, ubuf, nullptr, FF, HID);
  // 8) silu(g)*u -> gbuf (in place)
  silu_mul_kernel<<<((size_t)SEQ * FF) / 1024, 256, 0, stream>>>(gbuf, ubuf,
                                                                 gbuf);
  // 9) down-proj + residual -> out (fp32)
  gemm_kernel<1><<<dim3(SEQ / 128, HID / 128), 256, 0, stream>>>(
      gbuf, wd, d_out, h2, HID, FF);
}

// Round 2
// 1591.963 us; speedup vs baseline: 1.8846x; 1.8846x over previous
//
#include <hip/hip_runtime.h>

typedef short bf16x8 __attribute__((ext_vector_type(8)));
typedef float f32x4 __attribute__((ext_vector_type(4)));

#define DEV __device__ __forceinline__

constexpr int SEQ = 2048;
constexpr int HID = 4096;
constexpr int NH  = 32;
constexpr int NKV = 8;
constexpr int DH  = 128;
constexpr int FF  = 14336;
constexpr int QKVN = NH * DH + 2 * NKV * DH;  // 6144

DEV unsigned short f2bf(float f) {
  union { float f; unsigned u; } x; x.f = f;
  unsigned r = x.u + 0x7fffu + ((x.u >> 16) & 1u);
  return (unsigned short)(r >> 16);
}
DEV float bf2f(unsigned short u) {
  union { unsigned u; float f; } x; x.u = ((unsigned)u) << 16; return x.f;
}
DEV void gload16(const void* g, void* l) {
  __builtin_amdgcn_global_load_lds(
      (const __attribute__((address_space(1))) unsigned*)g,
      (__attribute__((address_space(3))) unsigned*)l, 16, 0, 0);
}

// ---------------------------------------------------------------- RMSNorm
__global__ __launch_bounds__(256) void rmsnorm_kernel(
    const float* __restrict__ x, const float* __restrict__ w,
    unsigned short* __restrict__ out) {
  const int row = blockIdx.x;
  const int tid = threadIdx.x;
  const float* xr = x + (size_t)row * HID;
  float4 v[4];
  float ss = 0.f;
#pragma unroll
  for (int i = 0; i < 4; ++i) {
    v[i] = *(const float4*)(xr + i * 1024 + tid * 4);
    ss += v[i].x * v[i].x + v[i].y * v[i].y + v[i].z * v[i].z + v[i].w * v[i].w;
  }
#pragma unroll
  for (int m = 1; m < 64; m <<= 1) ss += __shfl_xor(ss, m);
  __shared__ float red[4];
  if ((tid & 63) == 0) red[tid >> 6] = ss;
  __syncthreads();
  float tot = red[0] + red[1] + red[2] + red[3];
  float rms = rsqrtf(tot / (float)HID + 1e-5f);
  unsigned short* orow = out + (size_t)row * HID;
#pragma unroll
  for (int i = 0; i < 4; ++i) {
    int base = i * 1024 + tid * 4;
    ushort4 o;
    o.x = f2bf(v[i].x * rms * w[base + 0]);
    o.y = f2bf(v[i].y * rms * w[base + 1]);
    o.z = f2bf(v[i].z * rms * w[base + 2]);
    o.w = f2bf(v[i].w * rms * w[base + 3]);
    *(ushort4*)(orow + base) = o;
  }
}

// ------------------------------------------------- weight transpose+convert
// W[K][N] fp32 -> WT[N][K] bf16. grid (K/64, N/64), 256 threads.
__global__ __launch_bounds__(256) void wtrans_kernel(
    const float* __restrict__ W, unsigned short* __restrict__ WT, int K,
    int N) {
  __shared__ unsigned short t[64][72];
  const int k0 = blockIdx.x * 64, n0 = blockIdx.y * 64;
  const int tid = threadIdx.x;
  const int tk = tid >> 4;            // 0..15
  const int tn4 = (tid & 15) * 4;     // 0..60
#pragma unroll
  for (int p = 0; p < 4; ++p) {
    int k = tk + p * 16;
    float4 v = *(const float4*)(W + (size_t)(k0 + k) * N + n0 + tn4);
    t[tn4 + 0][k] = f2bf(v.x);
    t[tn4 + 1][k] = f2bf(v.y);
    t[tn4 + 2][k] = f2bf(v.z);
    t[tn4 + 3][k] = f2bf(v.w);
  }
  __syncthreads();
#pragma unroll
  for (int p = 0; p < 4; ++p) {
    int n = tk + p * 16;
    ushort4 o = *(const ushort4*)&t[n][tn4];
    *(ushort4*)(WT + (size_t)(n0 + n) * K + k0 + tn4) = o;
  }
}

// ---------------------------------------------------------------- RoPE (in-place, strided)
__global__ __launch_bounds__(256) void rope_kernel(unsigned short* __restrict__ x,
                                                   int nheads, int ld) {
  const int gid = blockIdx.x * 256 + threadIdx.x;
  const int i = gid & 63;
  const int t = gid >> 6;
  const int s = t / nheads;
  const int hh = t - s * nheads;
  float ang = (float)s * exp2f((float)i * (-29.897352853986263f / 64.f));
  float sn, cs;
  sincosf(ang, &sn, &cs);
  size_t base = (size_t)s * ld + hh * DH + i;
  float x1 = bf2f(x[base]);
  float x2 = bf2f(x[base + 64]);
  x[base]      = f2bf(x1 * cs - x2 * sn);
  x[base + 64] = f2bf(x2 * cs + x1 * sn);
}

// ---------------------------------------------------------------- SiLU(g)*u
__global__ __launch_bounds__(256) void silu_mul_kernel(
    const unsigned short* __restrict__ g, const unsigned short* __restrict__ u,
    unsigned short* __restrict__ out) {
  const size_t idx = ((size_t)blockIdx.x * 256 + threadIdx.x) * 4;
  ushort4 gv = *(const ushort4*)(g + idx);
  ushort4 uv = *(const ushort4*)(u + idx);
  float gf[4] = {bf2f(gv.x), bf2f(gv.y), bf2f(gv.z), bf2f(gv.w)};
  float uf[4] = {bf2f(uv.x), bf2f(uv.y), bf2f(uv.z), bf2f(uv.w)};
  ushort4 o;
  unsigned short* op = (unsigned short*)&o;
#pragma unroll
  for (int j = 0; j < 4; ++j) {
    float sl = gf[j] / (1.f + __expf(-gf[j]));
    op[j] = f2bf(sl * uf[j]);
  }
  *(ushort4*)(out + idx) = o;
}

// ---------------------------------------------------------------- GEMM (B^T)
// C[M,N] = A[M,K](bf16,row) @ BT[N,K](bf16,row)^T
// EPI=0: C bf16.  EPI=1: C fp32 = acc + res[M,N](fp32).
// 128x128 tile, BK=64, 4 waves (2x2 of 64x64), mfma 16x16x32 bf16.
// 1D grid (nwg % 8 == 0), bijective XCD chunking, m-fastest.
template <int EPI>
__global__ __launch_bounds__(256, 2) void gemm_bt_kernel(
    const unsigned short* __restrict__ A, const unsigned short* __restrict__ BT,
    void* __restrict__ Cv, const float* __restrict__ res, int gridM, int N,
    int K) {
  __shared__ __align__(128) char sm[2 * 128 * 64 * 2];  // 16KB A + 16KB B
  char* sA = sm;
  char* sB = sm + 16384;
  const int nwg = gridDim.x;
  const int b = blockIdx.x;
  const int logical = (b & 7) * (nwg >> 3) + (b >> 3);
  const int m0 = (logical % gridM) * 128;
  const int n0 = (logical / gridM) * 128;
  const int tid  = threadIdx.x;
  const int lane = tid & 63;
  const int wv   = tid >> 6;
  const int wm = (wv >> 1) * 64;
  const int wn = (wv & 1) * 64;

  f32x4 acc[4][4] = {};

  // staging geometry: lds linear [row(128)][kbyte(128)], XOR-swizzled source
  const int oA   = wv * 1024 + lane * 16;
  const int rowA = oA >> 7;  // + 32*i
  const int cA   = oA & 127;

  for (int kt = 0; kt < K; kt += 64) {
    __syncthreads();
#pragma unroll
    for (int i = 0; i < 4; ++i) {
      int row = rowA + 32 * i;
      int swc = cA ^ ((row & 7) << 4);
      const char* gpA =
          (const char*)A + ((size_t)(m0 + row) * K + kt) * 2 + swc;
      gload16(gpA, sA + i * 4096 + wv * 1024);
      const char* gpB =
          (const char*)BT + ((size_t)(n0 + row) * K + kt) * 2 + swc;
      gload16(gpB, sB + i * 4096 + wv * 1024);
    }
    __syncthreads();
#pragma unroll
    for (int kk = 0; kk < 2; ++kk) {
      const int kb = ((lane >> 4) * 16) + kk * 64;
      bf16x8 af[4], bfr[4];
#pragma unroll
      for (int mi = 0; mi < 4; ++mi) {
        int row = wm + mi * 16 + (lane & 15);
        af[mi] = *(const bf16x8*)(sA + ((row * 128 + kb) ^ ((row & 7) << 4)));
      }
#pragma unroll
      for (int ni = 0; ni < 4; ++ni) {
        int col = wn + ni * 16 + (lane & 15);
        bfr[ni] = *(const bf16x8*)(sB + ((col * 128 + kb) ^ ((col & 7) << 4)));
      }
#pragma unroll
      for (int mi = 0; mi < 4; ++mi)
#pragma unroll
        for (int ni = 0; ni < 4; ++ni)
          acc[mi][ni] = __builtin_amdgcn_mfma_f32_16x16x32_bf16(
              af[mi], bfr[ni], acc[mi][ni], 0, 0, 0);
    }
  }

  const int rbase = (lane >> 4) * 4;
  const int cbase = lane & 15;
#pragma unroll
  for (int mi = 0; mi < 4; ++mi)
#pragma unroll
    for (int ni = 0; ni < 4; ++ni)
#pragma unroll
      for (int r = 0; r < 4; ++r) {
        size_t row = (size_t)(m0 + wm + mi * 16 + rbase + r);
        size_t col = (size_t)(n0 + wn + ni * 16 + cbase);
        float vv = acc[mi][ni][r];
        if (EPI == 0) {
          ((unsigned short*)Cv)[row * N + col] = f2bf(vv);
        } else {
          ((float*)Cv)[row * N + col] = vv + res[row * N + col];
        }
      }
}

// ---------------------------------------------------------------- Flash attention
// grid (SEQ/64, NH). Block: 4 waves, each owns 16 q-rows. KV tiles of 64.
// Q/K/V live in the fused qkv buffer: row stride QKVN; Q at col 0, K at
// col NH*DH, V at col NH*DH + NKV*DH.
__global__ __launch_bounds__(256, 2) void attn_kernel(
    const unsigned short* __restrict__ QKV, unsigned short* __restrict__ Ob) {
  __shared__ __align__(128) char sm[16384 * 3 + 8192];  // Q,K,V^T,P
  char* sQ = sm;
  char* sK = sm + 16384;
  char* sV = sm + 32768;
  char* sP = sm + 49152;
  const int tid  = threadIdx.x;
  const int lane = tid & 63;
  const int wv   = tid >> 6;
  const int qb0  = blockIdx.x * 64;
  const int h    = blockIdx.y;
  const int hkv  = h >> 2;  // G = 4
  const int rbase = (lane >> 4) * 4;
  const int cbase = lane & 15;
  const unsigned short* Qp = QKV + h * DH;
  const unsigned short* Kp = QKV + NH * DH + hkv * DH;
  const unsigned short* Vp = QKV + NH * DH + NKV * DH + hkv * DH;

  // ---- stage Q (64 x 128 bf16, 256B rows, swizzle (row&15)<<4)
  const int oQ   = wv * 1024 + lane * 16;
  const int rowQ = oQ >> 8;  // + 16*i
  const int cQ   = oQ & 255;
#pragma unroll
  for (int i = 0; i < 4; ++i) {
    int row = rowQ + 16 * i;
    const char* gp = (const char*)Qp + ((size_t)(qb0 + row) * QKVN) * 2 +
                     (cQ ^ ((row & 15) << 4));
    gload16(gp, sQ + i * 4096 + wv * 1024);
  }

  f32x4 oacc[8] = {};
  float m_r[4] = {-1e30f, -1e30f, -1e30f, -1e30f};
  float l_r[4] = {0.f, 0.f, 0.f, 0.f};

  const int d4   = (tid & 31) * 4;
  const int kv2b = (tid >> 5) * 2;
  const int ntiles = blockIdx.x + 1;

  for (int t = 0; t < ntiles; ++t) {
    const int kt0 = t * 64;
    __syncthreads();
    // ---- stage K tile
#pragma unroll
    for (int i = 0; i < 4; ++i) {
      int row = rowQ + 16 * i;
      const char* gp = (const char*)Kp + ((size_t)(kt0 + row) * QKVN) * 2 +
                       (cQ ^ ((row & 15) << 4));
      gload16(gp, sK + i * 4096 + wv * 1024);
    }
    // ---- stage V^T tile: [d(128)][kv(64)] bf16, 128B rows
#pragma unroll
    for (int i = 0; i < 4; ++i) {
      int kv2 = kv2b + 16 * i;
      const unsigned short* g0 = Vp + (size_t)(kt0 + kv2) * QKVN + d4;
      ushort4 r0 = *(const ushort4*)g0;
      ushort4 r1 = *(const ushort4*)(g0 + QKVN);
      unsigned short a0[4] = {r0.x, r0.y, r0.z, r0.w};
      unsigned short a1[4] = {r1.x, r1.y, r1.z, r1.w};
#pragma unroll
      for (int j = 0; j < 4; ++j) {
        int dd = d4 + j;
        *(unsigned*)(sV + ((dd * 128 + kv2 * 2) ^ ((dd & 7) << 4))) =
            (unsigned)a0[j] | ((unsigned)a1[j] << 16);
      }
    }
    __syncthreads();

    // ---- S = Q K^T (wave: 16 q x 64 kv)
    f32x4 sacc[4] = {};
#pragma unroll
    for (int kk = 0; kk < 4; ++kk) {
      int kb = (lane >> 4) * 16 + kk * 64;
      int qrow = wv * 16 + (lane & 15);
      bf16x8 aq =
          *(const bf16x8*)(sQ + ((qrow * 256 + kb) ^ ((qrow & 15) << 4)));
#pragma unroll
      for (int ni = 0; ni < 4; ++ni) {
        int krow = ni * 16 + (lane & 15);
        bf16x8 bk =
            *(const bf16x8*)(sK + ((krow * 256 + kb) ^ ((krow & 15) << 4)));
        sacc[ni] =
            __builtin_amdgcn_mfma_f32_16x16x32_bf16(aq, bk, sacc[ni], 0, 0, 0);
      }
    }

    // ---- online softmax
    const float scale = 0.08838834764831845f;  // 1/sqrt(128)
#pragma unroll
    for (int r = 0; r < 4; ++r) {
      int qg = qb0 + wv * 16 + rbase + r;
      float mx = -1e30f;
#pragma unroll
      for (int ni = 0; ni < 4; ++ni) {
        int cg = kt0 + ni * 16 + cbase;
        float sv = sacc[ni][r] * scale;
        sv = (cg <= qg) ? sv : -1e30f;
        sacc[ni][r] = sv;
        mx = fmaxf(mx, sv);
      }
      mx = fmaxf(mx, __shfl_xor(mx, 1));
      mx = fmaxf(mx, __shfl_xor(mx, 2));
      mx = fmaxf(mx, __shfl_xor(mx, 4));
      mx = fmaxf(mx, __shfl_xor(mx, 8));
      float mnew = fmaxf(m_r[r], mx);
      float sf = __expf(m_r[r] - mnew);
      m_r[r] = mnew;
      float rsum = 0.f;
#pragma unroll
      for (int ni = 0; ni < 4; ++ni) {
        float pv = __expf(sacc[ni][r] - mnew);
        sacc[ni][r] = pv;
        rsum += pv;
      }
      rsum += __shfl_xor(rsum, 1);
      rsum += __shfl_xor(rsum, 2);
      rsum += __shfl_xor(rsum, 4);
      rsum += __shfl_xor(rsum, 8);
      l_r[r] = l_r[r] * sf + rsum;
#pragma unroll
      for (int nt = 0; nt < 8; ++nt) oacc[nt][r] *= sf;
    }

    // ---- P -> LDS (per-wave [16][64] bf16 region), then PV
    char* pw = sP + wv * 2048;
#pragma unroll
    for (int ni = 0; ni < 4; ++ni)
#pragma unroll
      for (int r = 0; r < 4; ++r) {
        int row = rbase + r;
        int cb2 = (ni * 16 + cbase) * 2;
        *(unsigned short*)(pw + ((row * 128 + cb2) ^ ((row & 7) << 4))) =
            f2bf(sacc[ni][r]);
      }
    asm volatile("s_waitcnt lgkmcnt(0)" ::: "memory");

#pragma unroll
    for (int kk = 0; kk < 2; ++kk) {
      int kb = (lane >> 4) * 16 + kk * 64;
      int prow = lane & 15;
      bf16x8 ap =
          *(const bf16x8*)(pw + ((prow * 128 + kb) ^ ((prow & 7) << 4)));
#pragma unroll
      for (int nt = 0; nt < 8; ++nt) {
        int vrow = nt * 16 + (lane & 15);
        bf16x8 bv =
            *(const bf16x8*)(sV + ((vrow * 128 + kb) ^ ((vrow & 7) << 4)));
        oacc[nt] =
            __builtin_amdgcn_mfma_f32_16x16x32_bf16(ap, bv, oacc[nt], 0, 0, 0);
      }
    }
  }

  // ---- epilogue: O / l
#pragma unroll
  for (int nt = 0; nt < 8; ++nt)
#pragma unroll
    for (int r = 0; r < 4; ++r) {
      size_t row = (size_t)(qb0 + wv * 16 + rbase + r);
      int col = nt * 16 + cbase;
      Ob[row * (NH * DH) + h * DH + col] = f2bf(oacc[nt][r] / l_r[r]);
    }
}

// ---------------------------------------------------------------- host
extern "C" void kernel_launch(void* const* d_in, const int* in_sizes, int n_in,
                              void* d_out, int out_size, void* d_ws,
                              size_t ws_size, hipStream_t stream) {
  const float* hs  = (const float*)d_in[0];
  const float* wq  = (const float*)d_in[1];
  const float* wk  = (const float*)d_in[2];
  const float* wvp = (const float*)d_in[3];
  const float* wo  = (const float*)d_in[4];
  const float* wg  = (const float*)d_in[5];
  const float* wu  = (const float*)d_in[6];
  const float* wd  = (const float*)d_in[7];
  const float* ln1 = (const float*)d_in[8];
  const float* ln2 = (const float*)d_in[9];

  char* p = (char*)d_ws;
  size_t need = 0;
  auto alloc = [&](size_t bytes) {
    char* r = p + need;
    need += (bytes + 255) & ~(size_t)255;
    return r;
  };
  unsigned short* T1   = (unsigned short*)alloc((size_t)FF * HID * 2);  // 117MB
  unsigned short* xn   = (unsigned short*)alloc((size_t)SEQ * HID * 2);
  unsigned short* qkv  = (unsigned short*)alloc((size_t)SEQ * QKVN * 2);
  unsigned short* ab   = (unsigned short*)alloc((size_t)SEQ * NH * DH * 2);
  float*          h2   = (float*)alloc((size_t)SEQ * HID * 4);
  unsigned short* xn2  = (unsigned short*)alloc((size_t)SEQ * HID * 2);
  unsigned short* gbuf = (unsigned short*)alloc((size_t)SEQ * FF * 2);
  unsigned short* ubuf = (unsigned short*)alloc((size_t)SEQ * FF * 2);
  if (need > ws_size) return;  // workspace too small: fail visibly

  // 1) rmsnorm1
  rmsnorm_kernel<<<SEQ, 256, 0, stream>>>(hs, ln1, xn);
  // 2) transpose wq|wk|wv into T1 -> [QKVN][HID] bf16
  wtrans_kernel<<<dim3(HID / 64, HID / 64), 256, 0, stream>>>(wq, T1, HID, HID);
  wtrans_kernel<<<dim3(HID / 64, (NKV * DH) / 64), 256, 0, stream>>>(
      wk, T1 + (size_t)(NH * DH) * HID, HID, NKV * DH);
  wtrans_kernel<<<dim3(HID / 64, (NKV * DH) / 64), 256, 0, stream>>>(
      wvp, T1 + (size_t)(NH * DH + NKV * DH) * HID, HID, NKV * DH);
  // 3) fused qkv projection
  gemm_bt_kernel<0><<<(SEQ / 128) * (QKVN / 128), 256, 0, stream>>>(
      xn, T1, qkv, nullptr, SEQ / 128, QKVN, HID);
  // 4) RoPE (in place on q and k slices)
  rope_kernel<<<(SEQ * NH * 64) / 256, 256, 0, stream>>>(qkv, NH, QKVN);
  rope_kernel<<<(SEQ * NKV * 64) / 256, 256, 0, stream>>>(qkv + NH * DH, NKV,
                                                          QKVN);
  // 5) attention
  attn_kernel<<<dim3(SEQ / 64, NH), 256, 0, stream>>>(qkv, ab);
  // 6) o-proj + residual -> h2 (fp32)
  wtrans_kernel<<<dim3(HID / 64, HID / 64), 256, 0, stream>>>(wo, T1, HID, HID);
  gemm_bt_kernel<1><<<(SEQ / 128) * (HID / 128), 256, 0, stream>>>(
      ab, T1, h2, hs, SEQ / 128, HID, HID);
  // 7) rmsnorm2
  rmsnorm_kernel<<<SEQ, 256, 0, stream>>>(h2, ln2, xn2);
  // 8) gate
  wtrans_kernel<<<dim3(HID / 64, FF / 64), 256, 0, stream>>>(wg, T1, HID, FF);
  gemm_bt_kernel<0><<<(SEQ / 128) * (FF / 128), 256, 0, stream>>>(
      xn2, T1, gbuf, nullptr, SEQ / 128, FF, HID);
  // 9) up
  wtrans_kernel<<<dim3(HID / 64, FF / 64), 256, 0, stream>>>(wu, T1, HID, FF);
  gemm_bt_kernel<0><<<(SEQ / 128) * (FF / 128), 256, 0, stream>>>(
      xn2, T1, ubuf, nullptr, SEQ / 128, FF, HID);
  // 10) silu(g)*u -> gbuf (in place)
  silu_mul_kernel<<<((size_t)SEQ * FF) / 1024, 256, 0, stream>>>(gbuf, ubuf,
                                                                 gbuf);
  // 11) down-proj + residual -> out (fp32)
  wtrans_kernel<<<dim3(FF / 64, HID / 64), 256, 0, stream>>>(wd, T1, FF, HID);
  gemm_bt_kernel<1><<<(SEQ / 128) * (HID / 128), 256, 0, stream>>>(
      gbuf, T1, d_out, h2, SEQ / 128, HID, FF);
}

// Round 3
// 1435.532 us; speedup vs baseline: 2.0899x; 1.1090x over previous
//
#include <hip/hip_runtime.h>

typedef short bf16x8 __attribute__((ext_vector_type(8)));
typedef float f32x4 __attribute__((ext_vector_type(4)));

#define DEV __device__ __forceinline__

constexpr int SEQ = 2048;
constexpr int HID = 4096;
constexpr int NH  = 32;
constexpr int NKV = 8;
constexpr int DH  = 128;
constexpr int FF  = 14336;
constexpr int QKVN = NH * DH + 2 * NKV * DH;  // 6144

DEV unsigned short f2bf(float f) {
  union { float f; unsigned u; } x; x.f = f;
  unsigned r = x.u + 0x7fffu + ((x.u >> 16) & 1u);
  return (unsigned short)(r >> 16);
}
DEV float bf2f(unsigned short u) {
  union { unsigned u; float f; } x; x.u = ((unsigned)u) << 16; return x.f;
}
DEV void gload16(const void* g, void* l) {
  __builtin_amdgcn_global_load_lds(
      (const __attribute__((address_space(1))) unsigned*)g,
      (__attribute__((address_space(3))) unsigned*)l, 16, 0, 0);
}

// ---------------------------------------------------------------- RMSNorm
__global__ __launch_bounds__(256) void rmsnorm_kernel(
    const float* __restrict__ x, const float* __restrict__ w,
    unsigned short* __restrict__ out) {
  const int row = blockIdx.x;
  const int tid = threadIdx.x;
  const float* xr = x + (size_t)row * HID;
  float4 v[4];
  float ss = 0.f;
#pragma unroll
  for (int i = 0; i < 4; ++i) {
    v[i] = *(const float4*)(xr + i * 1024 + tid * 4);
    ss += v[i].x * v[i].x + v[i].y * v[i].y + v[i].z * v[i].z + v[i].w * v[i].w;
  }
#pragma unroll
  for (int m = 1; m < 64; m <<= 1) ss += __shfl_xor(ss, m);
  __shared__ float red[4];
  if ((tid & 63) == 0) red[tid >> 6] = ss;
  __syncthreads();
  float tot = red[0] + red[1] + red[2] + red[3];
  float rms = rsqrtf(tot / (float)HID + 1e-5f);
  unsigned short* orow = out + (size_t)row * HID;
#pragma unroll
  for (int i = 0; i < 4; ++i) {
    int base = i * 1024 + tid * 4;
    ushort4 o;
    o.x = f2bf(v[i].x * rms * w[base + 0]);
    o.y = f2bf(v[i].y * rms * w[base + 1]);
    o.z = f2bf(v[i].z * rms * w[base + 2]);
    o.w = f2bf(v[i].w * rms * w[base + 3]);
    *(ushort4*)(orow + base) = o;
  }
}

// ------------------------------------------------- weight transpose+convert
// W[K][N] fp32 -> WT[N][K] bf16. grid (K/64, N/64), 256 threads.
__global__ __launch_bounds__(256) void wtrans_kernel(
    const float* __restrict__ W, unsigned short* __restrict__ WT, int K,
    int N) {
  __shared__ unsigned short t[64][72];
  const int k0 = blockIdx.x * 64, n0 = blockIdx.y * 64;
  const int tid = threadIdx.x;
  const int tk = tid >> 4;            // 0..15
  const int tn4 = (tid & 15) * 4;     // 0..60
#pragma unroll
  for (int p = 0; p < 4; ++p) {
    int k = tk + p * 16;
    float4 v = *(const float4*)(W + (size_t)(k0 + k) * N + n0 + tn4);
    t[tn4 + 0][k] = f2bf(v.x);
    t[tn4 + 1][k] = f2bf(v.y);
    t[tn4 + 2][k] = f2bf(v.z);
    t[tn4 + 3][k] = f2bf(v.w);
  }
  __syncthreads();
#pragma unroll
  for (int p = 0; p < 4; ++p) {
    int n = tk + p * 16;
    ushort4 o = *(const ushort4*)&t[n][tn4];
    *(ushort4*)(WT + (size_t)(n0 + n) * K + k0 + tn4) = o;
  }
}

// ---------------------------------------------------------------- RoPE (in-place, strided)
__global__ __launch_bounds__(256) void rope_kernel(unsigned short* __restrict__ x,
                                                   int nheads, int ld) {
  const int gid = blockIdx.x * 256 + threadIdx.x;
  const int i = gid & 63;
  const int t = gid >> 6;
  const int s = t / nheads;
  const int hh = t - s * nheads;
  float ang = (float)s * exp2f((float)i * (-29.897352853986263f / 64.f));
  float sn, cs;
  sincosf(ang, &sn, &cs);
  size_t base = (size_t)s * ld + hh * DH + i;
  float x1 = bf2f(x[base]);
  float x2 = bf2f(x[base + 64]);
  x[base]      = f2bf(x1 * cs - x2 * sn);
  x[base + 64] = f2bf(x2 * cs + x1 * sn);
}

// ---------------------------------------------------------------- SiLU(g)*u
__global__ __launch_bounds__(256) void silu_mul_kernel(
    const unsigned short* __restrict__ g, const unsigned short* __restrict__ u,
    unsigned short* __restrict__ out) {
  const size_t idx = ((size_t)blockIdx.x * 256 + threadIdx.x) * 4;
  ushort4 gv = *(const ushort4*)(g + idx);
  ushort4 uv = *(const ushort4*)(u + idx);
  float gf[4] = {bf2f(gv.x), bf2f(gv.y), bf2f(gv.z), bf2f(gv.w)};
  float uf[4] = {bf2f(uv.x), bf2f(uv.y), bf2f(uv.z), bf2f(uv.w)};
  ushort4 o;
  unsigned short* op = (unsigned short*)&o;
#pragma unroll
  for (int j = 0; j < 4; ++j) {
    float sl = gf[j] / (1.f + __expf(-gf[j]));
    op[j] = f2bf(sl * uf[j]);
  }
  *(ushort4*)(out + idx) = o;
}

// ---------------------------------------------------------------- GEMM 8-phase
// C[M,N] = A[M,K](bf16,row) @ BT[N,K](bf16,row)^T
// Tile BM x 256, BM = 2*WROWS; BK=64; 512 threads = 8 waves (2M x 4N).
// Double-buffered LDS; counted vmcnt (T3+T4); setprio around MFMA (T5).
// Staging halves per K-tile: h0=B[0:128), h1=B[128:256), h2=A[0:128),
// (h3=A[128:256) if BM==256). Issue map per tile t:
//   phase1: (t+1, last A-half)   phase2: (t+2, h0)
//   phase3: (t+2, h1)            phase4: (t+2, h2 if H==4); vmcnt(2H-2)
// Ledger: steady-state in-flight = (H-1) halves = 2H-2 loads; every
// prefetch lands >=1 barrier after its region's last ds_read.
// EPI=0: C bf16.  EPI=1: C fp32 = acc + res[M,N](fp32).
template <int WROWS, int EPI>
__global__ __launch_bounds__(512, 2) void gemm8p_kernel(
    const unsigned short* __restrict__ A, const unsigned short* __restrict__ BT,
    void* __restrict__ Cv, const float* __restrict__ res, int gridM, int N,
    int K) {
  constexpr int BM = 2 * WROWS;
  constexpr int MF = WROWS / 32;   // m-frags per quadrant
  constexpr int H  = 2 + BM / 128; // staging halves per K-tile
  constexpr int ABYTES = BM * 128;
  constexpr int BUFBYTES = ABYTES + 32768;
  __shared__ __align__(128) char sm[2 * BUFBYTES];

  const int tid  = threadIdx.x;
  const int lane = tid & 63;
  const int wv   = tid >> 6;
  const int nwg = gridDim.x;
  const int b = blockIdx.x;
  const int logical = (b & 7) * (nwg >> 3) + (b >> 3);
  const int m0 = (logical % gridM) * BM;
  const int n0 = (logical / gridM) * 256;
  const int wm = (wv >> 2) * WROWS;
  const int wn = (wv & 3) * 64;
  const int nt = K >> 6;

  // staging geometry: thread loads 16B; row = tid/8, byte-col = (tid&7)*16
  const int srow = tid >> 3;
  const int scolb = (tid & 7) * 16;
  const int sldsbase = wv * 1024;  // HW adds lane*16

  auto stage = [&](int h, int t) {
    const int buf = t & 1;
    const int kt = t * 64;
    char* ldsOp;
    const unsigned short* g;
    int grow0, rowBase;
    if (h < 2) {
      ldsOp = sm + buf * BUFBYTES + ABYTES; g = BT; grow0 = n0; rowBase = h * 128;
    } else {
      ldsOp = sm + buf * BUFBYTES;          g = A;  grow0 = m0; rowBase = (h - 2) * 128;
    }
#pragma unroll
    for (int r = 0; r < 2; ++r) {
      int row = rowBase + r * 64 + srow;
      const char* gp = (const char*)g + ((size_t)(grow0 + row) * K + kt) * 2 +
                       (scolb ^ ((row & 7) << 4));
      gload16(gp, ldsOp + rowBase * 128 + r * 8192 + sldsbase);
    }
  };

  const int kb0 = (lane >> 4) * 16;
  const int lrow = lane & 15;
  auto ldA = [&](const char* sA, int mh, int mf, int ks) {
    int row = wm + mh * (WROWS / 2) + mf * 16 + lrow;
    return *(const bf16x8*)(sA + ((row * 128 + kb0 + ks * 64) ^ ((row & 7) << 4)));
  };
  auto ldB = [&](const char* sB, int j, int ks) {
    int col = wn + (j >> 1) * 32 + (j & 1) * 16 + lrow;
    return *(const bf16x8*)(sB + ((col * 128 + kb0 + ks * 64) ^ ((col & 7) << 4)));
  };

  f32x4 acc[2 * MF][4] = {};

  // ---- prologue: tile0 all halves + tile1 first H-1 halves
#pragma unroll
  for (int h = 0; h < H; ++h) stage(h, 0);
#pragma unroll
  for (int h = 0; h < H - 1; ++h) stage(h, 1);
  if (H == 4) asm volatile("s_waitcnt vmcnt(6)" ::: "memory");
  else        asm volatile("s_waitcnt vmcnt(4)" ::: "memory");
  __builtin_amdgcn_s_barrier();

  for (int t = 0; t < nt; ++t) {
    const char* sA = sm + (t & 1) * BUFBYTES;
    const char* sB = sA + ABYTES;
    bf16x8 a[MF][2], bb[4][2];

    // ---- phase 1: read A0 + all B; prefetch (t+1, last A-half); MFMA (0,0)
#pragma unroll
    for (int mf = 0; mf < MF; ++mf) {
      a[mf][0] = ldA(sA, 0, mf, 0);
      a[mf][1] = ldA(sA, 0, mf, 1);
    }
#pragma unroll
    for (int j = 0; j < 4; ++j) {
      bb[j][0] = ldB(sB, j, 0);
      bb[j][1] = ldB(sB, j, 1);
    }
    if (t + 1 < nt) stage(H - 1, t + 1);
    __builtin_amdgcn_sched_barrier(0);
    __builtin_amdgcn_s_barrier();
    __builtin_amdgcn_s_setprio(1);
#pragma unroll
    for (int mf = 0; mf < MF; ++mf)
#pragma unroll
      for (int nf = 0; nf < 2; ++nf)
#pragma unroll
        for (int ks = 0; ks < 2; ++ks)
          acc[mf][nf] = __builtin_amdgcn_mfma_f32_16x16x32_bf16(
              a[mf][ks], bb[nf][ks], acc[mf][nf], 0, 0, 0);
    __builtin_amdgcn_s_setprio(0);
    __builtin_amdgcn_sched_barrier(0);
    __builtin_amdgcn_s_barrier();

    // ---- phase 2: prefetch (t+2, h0); MFMA (0,1)
    if (t + 2 < nt) stage(0, t + 2);
    __builtin_amdgcn_sched_barrier(0);
    __builtin_amdgcn_s_barrier();
    __builtin_amdgcn_s_setprio(1);
#pragma unroll
    for (int mf = 0; mf < MF; ++mf)
#pragma unroll
      for (int nf = 0; nf < 2; ++nf)
#pragma unroll
        for (int ks = 0; ks < 2; ++ks)
          acc[mf][2 + nf] = __builtin_amdgcn_mfma_f32_16x16x32_bf16(
              a[mf][ks], bb[2 + nf][ks], acc[mf][2 + nf], 0, 0, 0);
    __builtin_amdgcn_s_setprio(0);
    __builtin_amdgcn_sched_barrier(0);
    __builtin_amdgcn_s_barrier();

    // ---- phase 3: read A1; prefetch (t+2, h1); MFMA (1,0)
#pragma unroll
    for (int mf = 0; mf < MF; ++mf) {
      a[mf][0] = ldA(sA, 1, mf, 0);
      a[mf][1] = ldA(sA, 1, mf, 1);
    }
    if (t + 2 < nt) stage(1, t + 2);
    __builtin_amdgcn_sched_barrier(0);
    __builtin_amdgcn_s_barrier();
    __builtin_amdgcn_s_setprio(1);
#pragma unroll
    for (int mf = 0; mf < MF; ++mf)
#pragma unroll
      for (int nf = 0; nf < 2; ++nf)
#pragma unroll
        for (int ks = 0; ks < 2; ++ks)
          acc[MF + mf][nf] = __builtin_amdgcn_mfma_f32_16x16x32_bf16(
              a[mf][ks], bb[nf][ks], acc[MF + mf][nf], 0, 0, 0);
    __builtin_amdgcn_s_setprio(0);
    __builtin_amdgcn_sched_barrier(0);
    __builtin_amdgcn_s_barrier();

    // ---- phase 4: prefetch (t+2, h2 if H==4); vmcnt; MFMA (1,1)
    if (H == 4 && t + 2 < nt) stage(2, t + 2);
    if (t + 2 < nt) {
      if (H == 4) asm volatile("s_waitcnt vmcnt(6)" ::: "memory");
      else        asm volatile("s_waitcnt vmcnt(4)" ::: "memory");
    } else {
      asm volatile("s_waitcnt vmcnt(0)" ::: "memory");
    }
    __builtin_amdgcn_sched_barrier(0);
    __builtin_amdgcn_s_barrier();
    __builtin_amdgcn_s_setprio(1);
#pragma unroll
    for (int mf = 0; mf < MF; ++mf)
#pragma unroll
      for (int nf = 0; nf < 2; ++nf)
#pragma unroll
        for (int ks = 0; ks < 2; ++ks)
          acc[MF + mf][2 + nf] = __builtin_amdgcn_mfma_f32_16x16x32_bf16(
              a[mf][ks], bb[2 + nf][ks], acc[MF + mf][2 + nf], 0, 0, 0);
    __builtin_amdgcn_s_setprio(0);
    __builtin_amdgcn_sched_barrier(0);
    __builtin_amdgcn_s_barrier();
  }

  // ---- epilogue
  const int rb = (lane >> 4) * 4;
#pragma unroll
  for (int i = 0; i < 2 * MF; ++i) {
    const int mh = i / MF, mf = i % MF;
#pragma unroll
    for (int j = 0; j < 4; ++j) {
#pragma unroll
      for (int r = 0; r < 4; ++r) {
        size_t row = (size_t)(m0 + wm + mh * (WROWS / 2) + mf * 16 + rb + r);
        size_t col = (size_t)(n0 + wn + (j >> 1) * 32 + (j & 1) * 16 + lrow);
        float vv = acc[i][j][r];
        if (EPI == 0) {
          ((unsigned short*)Cv)[row * N + col] = f2bf(vv);
        } else {
          ((float*)Cv)[row * N + col] = vv + res[row * N + col];
        }
      }
    }
  }
}

// ---------------------------------------------------------------- Flash attention
// grid (SEQ/64, NH). Block: 4 waves, each owns 16 q-rows. KV tiles of 64.
__global__ __launch_bounds__(256, 2) void attn_kernel(
    const unsigned short* __restrict__ QKV, unsigned short* __restrict__ Ob) {
  __shared__ __align__(128) char sm[16384 * 3 + 8192];  // Q,K,V^T,P
  char* sQ = sm;
  char* sK = sm + 16384;
  char* sV = sm + 32768;
  char* sP = sm + 49152;
  const int tid  = threadIdx.x;
  const int lane = tid & 63;
  const int wv   = tid >> 6;
  const int qb0  = blockIdx.x * 64;
  const int h    = blockIdx.y;
  const int hkv  = h >> 2;  // G = 4
  const int rbase = (lane >> 4) * 4;
  const int cbase = lane & 15;
  const unsigned short* Qp = QKV + h * DH;
  const unsigned short* Kp = QKV + NH * DH + hkv * DH;
  const unsigned short* Vp = QKV + NH * DH + NKV * DH + hkv * DH;

  const int oQ   = wv * 1024 + lane * 16;
  const int rowQ = oQ >> 8;  // + 16*i
  const int cQ   = oQ & 255;
#pragma unroll
  for (int i = 0; i < 4; ++i) {
    int row = rowQ + 16 * i;
    const char* gp = (const char*)Qp + ((size_t)(qb0 + row) * QKVN) * 2 +
                     (cQ ^ ((row & 15) << 4));
    gload16(gp, sQ + i * 4096 + wv * 1024);
  }

  f32x4 oacc[8] = {};
  float m_r[4] = {-1e30f, -1e30f, -1e30f, -1e30f};
  float l_r[4] = {0.f, 0.f, 0.f, 0.f};

  const int d4   = (tid & 31) * 4;
  const int kv2b = (tid >> 5) * 2;
  const int ntiles = blockIdx.x + 1;

  for (int t = 0; t < ntiles; ++t) {
    const int kt0 = t * 64;
    __syncthreads();
#pragma unroll
    for (int i = 0; i < 4; ++i) {
      int row = rowQ + 16 * i;
      const char* gp = (const char*)Kp + ((size_t)(kt0 + row) * QKVN) * 2 +
                       (cQ ^ ((row & 15) << 4));
      gload16(gp, sK + i * 4096 + wv * 1024);
    }
#pragma unroll
    for (int i = 0; i < 4; ++i) {
      int kv2 = kv2b + 16 * i;
      const unsigned short* g0 = Vp + (size_t)(kt0 + kv2) * QKVN + d4;
      ushort4 r0 = *(const ushort4*)g0;
      ushort4 r1 = *(const ushort4*)(g0 + QKVN);
      unsigned short a0[4] = {r0.x, r0.y, r0.z, r0.w};
      unsigned short a1[4] = {r1.x, r1.y, r1.z, r1.w};
#pragma unroll
      for (int j = 0; j < 4; ++j) {
        int dd = d4 + j;
        *(unsigned*)(sV + ((dd * 128 + kv2 * 2) ^ ((dd & 7) << 4))) =
            (unsigned)a0[j] | ((unsigned)a1[j] << 16);
      }
    }
    __syncthreads();

    f32x4 sacc[4] = {};
#pragma unroll
    for (int kk = 0; kk < 4; ++kk) {
      int kb = (lane >> 4) * 16 + kk * 64;
      int qrow = wv * 16 + (lane & 15);
      bf16x8 aq =
          *(const bf16x8*)(sQ + ((qrow * 256 + kb) ^ ((qrow & 15) << 4)));
#pragma unroll
      for (int ni = 0; ni < 4; ++ni) {
        int krow = ni * 16 + (lane & 15);
        bf16x8 bk =
            *(const bf16x8*)(sK + ((krow * 256 + kb) ^ ((krow & 15) << 4)));
        sacc[ni] =
            __builtin_amdgcn_mfma_f32_16x16x32_bf16(aq, bk, sacc[ni], 0, 0, 0);
      }
    }

    const float scale = 0.08838834764831845f;  // 1/sqrt(128)
#pragma unroll
    for (int r = 0; r < 4; ++r) {
      int qg = qb0 + wv * 16 + rbase + r;
      float mx = -1e30f;
#pragma unroll
      for (int ni = 0; ni < 4; ++ni) {
        int cg = kt0 + ni * 16 + cbase;
        float sv = sacc[ni][r] * scale;
        sv = (cg <= qg) ? sv : -1e30f;
        sacc[ni][r] = sv;
        mx = fmaxf(mx, sv);
      }
      mx = fmaxf(mx, __shfl_xor(mx, 1));
      mx = fmaxf(mx, __shfl_xor(mx, 2));
      mx = fmaxf(mx, __shfl_xor(mx, 4));
      mx = fmaxf(mx, __shfl_xor(mx, 8));
      float mnew = fmaxf(m_r[r], mx);
      float sf = __expf(m_r[r] - mnew);
      m_r[r] = mnew;
      float rsum = 0.f;
#pragma unroll
      for (int ni = 0; ni < 4; ++ni) {
        float pv = __expf(sacc[ni][r] - mnew);
        sacc[ni][r] = pv;
        rsum += pv;
      }
      rsum += __shfl_xor(rsum, 1);
      rsum += __shfl_xor(rsum, 2);
      rsum += __shfl_xor(rsum, 4);
      rsum += __shfl_xor(rsum, 8);
      l_r[r] = l_r[r] * sf + rsum;
#pragma unroll
      for (int nt = 0; nt < 8; ++nt) oacc[nt][r] *= sf;
    }

    char* pw = sP + wv * 2048;
#pragma unroll
    for (int ni = 0; ni < 4; ++ni)
#pragma unroll
      for (int r = 0; r < 4; ++r) {
        int row = rbase + r;
        int cb2 = (ni * 16 + cbase) * 2;
        *(unsigned short*)(pw + ((row * 128 + cb2) ^ ((row & 7) << 4))) =
            f2bf(sacc[ni][r]);
      }
    asm volatile("s_waitcnt lgkmcnt(0)" ::: "memory");

#pragma unroll
    for (int kk = 0; kk < 2; ++kk) {
      int kb = (lane >> 4) * 16 + kk * 64;
      int prow = lane & 15;
      bf16x8 ap =
          *(const bf16x8*)(pw + ((prow * 128 + kb) ^ ((prow & 7) << 4)));
#pragma unroll
      for (int nt = 0; nt < 8; ++nt) {
        int vrow = nt * 16 + (lane & 15);
        bf16x8 bv =
            *(const bf16x8*)(sV + ((vrow * 128 + kb) ^ ((vrow & 7) << 4)));
        oacc[nt] =
            __builtin_amdgcn_mfma_f32_16x16x32_bf16(ap, bv, oacc[nt], 0, 0, 0);
      }
    }
  }

#pragma unroll
  for (int nt = 0; nt < 8; ++nt)
#pragma unroll
    for (int r = 0; r < 4; ++r) {
      size_t row = (size_t)(qb0 + wv * 16 + rbase + r);
      int col = nt * 16 + cbase;
      Ob[row * (NH * DH) + h * DH + col] = f2bf(oacc[nt][r] / l_r[r]);
    }
}

// ---------------------------------------------------------------- host
extern "C" void kernel_launch(void* const* d_in, const int* in_sizes, int n_in,
                              void* d_out, int out_size, void* d_ws,
                              size_t ws_size, hipStream_t stream) {
  const float* hs  = (const float*)d_in[0];
  const float* wq  = (const float*)d_in[1];
  const float* wk  = (const float*)d_in[2];
  const float* wvp = (const float*)d_in[3];
  const float* wo  = (const float*)d_in[4];
  const float* wg  = (const float*)d_in[5];
  const float* wu  = (const float*)d_in[6];
  const float* wd  = (const float*)d_in[7];
  const float* ln1 = (const float*)d_in[8];
  const float* ln2 = (const float*)d_in[9];

  char* p = (char*)d_ws;
  size_t need = 0;
  auto alloc = [&](size_t bytes) {
    char* r = p + need;
    need += (bytes + 255) & ~(size_t)255;
    return r;
  };
  unsigned short* T1   = (unsigned short*)alloc((size_t)FF * HID * 2);  // 117MB
  unsigned short* xn   = (unsigned short*)alloc((size_t)SEQ * HID * 2);
  unsigned short* qkv  = (unsigned short*)alloc((size_t)SEQ * QKVN * 2);
  unsigned short* ab   = (unsigned short*)alloc((size_t)SEQ * NH * DH * 2);
  float*          h2   = (float*)alloc((size_t)SEQ * HID * 4);
  unsigned short* xn2  = (unsigned short*)alloc((size_t)SEQ * HID * 2);
  unsigned short* gbuf = (unsigned short*)alloc((size_t)SEQ * FF * 2);
  unsigned short* ubuf = (unsigned short*)alloc((size_t)SEQ * FF * 2);
  if (need > ws_size) return;  // workspace too small: fail visibly

  // 1) rmsnorm1
  rmsnorm_kernel<<<SEQ, 256, 0, stream>>>(hs, ln1, xn);
  // 2) transpose wq|wk|wv into T1 -> [QKVN][HID] bf16
  wtrans_kernel<<<dim3(HID / 64, HID / 64), 256, 0, stream>>>(wq, T1, HID, HID);
  wtrans_kernel<<<dim3(HID / 64, (NKV * DH) / 64), 256, 0, stream>>>(
      wk, T1 + (size_t)(NH * DH) * HID, HID, NKV * DH);
  wtrans_kernel<<<dim3(HID / 64, (NKV * DH) / 64), 256, 0, stream>>>(
      wvp, T1 + (size_t)(NH * DH + NKV * DH) * HID, HID, NKV * DH);
  // 3) fused qkv projection (grid 8*24=192)
  gemm8p_kernel<128, 0><<<(SEQ / 256) * (QKVN / 256), 512, 0, stream>>>(
      xn, T1, qkv, nullptr, SEQ / 256, QKVN, HID);
  // 4) RoPE (in place on q and k slices)
  rope_kernel<<<(SEQ * NH * 64) / 256, 256, 0, stream>>>(qkv, NH, QKVN);
  rope_kernel<<<(SEQ * NKV * 64) / 256, 256, 0, stream>>>(qkv + NH * DH, NKV,
                                                          QKVN);
  // 5) attention
  attn_kernel<<<dim3(SEQ / 64, NH), 256, 0, stream>>>(qkv, ab);
  // 6) o-proj + residual -> h2 (fp32); BM=128 -> grid 16*16=256 (full chip)
  wtrans_kernel<<<dim3(HID / 64, HID / 64), 256, 0, stream>>>(wo, T1, HID, HID);
  gemm8p_kernel<64, 1><<<(SEQ / 128) * (HID / 256), 512, 0, stream>>>(
      ab, T1, h2, hs, SEQ / 128, HID, HID);
  // 7) rmsnorm2
  rmsnorm_kernel<<<SEQ, 256, 0, stream>>>(h2, ln2, xn2);
  // 8) gate (grid 8*56=448)
  wtrans_kernel<<<dim3(HID / 64, FF / 64), 256, 0, stream>>>(wg, T1, HID, FF);
  gemm8p_kernel<128, 0><<<(SEQ / 256) * (FF / 256), 512, 0, stream>>>(
      xn2, T1, gbuf, nullptr, SEQ / 256, FF, HID);
  // 9) up
  wtrans_kernel<<<dim3(HID / 64, FF / 64), 256, 0, stream>>>(wu, T1, HID, FF);
  gemm8p_kernel<128, 0><<<(SEQ / 256) * (FF / 256), 512, 0, stream>>>(
      xn2, T1, ubuf, nullptr, SEQ / 256, FF, HID);
  // 10) silu(g)*u -> gbuf (in place)
  silu_mul_kernel<<<((size_t)SEQ * FF) / 1024, 256, 0, stream>>>(gbuf, ubuf,
                                                                 gbuf);
  // 11) down-proj + residual -> out (fp32); BM=128 -> grid 256
  wtrans_kernel<<<dim3(FF / 64, HID / 64), 256, 0, stream>>>(wd, T1, FF, HID);
  gemm8p_kernel<64, 1><<<(SEQ / 128) * (HID / 256), 512, 0, stream>>>(
      gbuf, T1, d_out, h2, SEQ / 128, HID, FF);
}

// Round 4
// 1301.188 us; speedup vs baseline: 2.3057x; 1.1032x over previous
//
#include <hip/hip_runtime.h>

typedef short bf16x8 __attribute__((ext_vector_type(8)));
typedef float f32x4 __attribute__((ext_vector_type(4)));

#define DEV __device__ __forceinline__

constexpr int SEQ = 2048;
constexpr int HID = 4096;
constexpr int NH  = 32;
constexpr int NKV = 8;
constexpr int DH  = 128;
constexpr int FF  = 14336;
constexpr int QKVN = NH * DH + 2 * NKV * DH;  // 6144

DEV unsigned short f2bf(float f) {
  union { float f; unsigned u; } x; x.f = f;
  unsigned r = x.u + 0x7fffu + ((x.u >> 16) & 1u);
  return (unsigned short)(r >> 16);
}
DEV float bf2f(unsigned short u) {
  union { unsigned u; float f; } x; x.u = ((unsigned)u) << 16; return x.f;
}
DEV void gload16(const void* g, void* l) {
  __builtin_amdgcn_global_load_lds(
      (const __attribute__((address_space(1))) unsigned*)g,
      (__attribute__((address_space(3))) unsigned*)l, 16, 0, 0);
}

// ---------------------------------------------------------------- RMSNorm
__global__ __launch_bounds__(256) void rmsnorm_kernel(
    const float* __restrict__ x, const float* __restrict__ w,
    unsigned short* __restrict__ out) {
  const int row = blockIdx.x;
  const int tid = threadIdx.x;
  const float* xr = x + (size_t)row * HID;
  float4 v[4];
  float ss = 0.f;
#pragma unroll
  for (int i = 0; i < 4; ++i) {
    v[i] = *(const float4*)(xr + i * 1024 + tid * 4);
    ss += v[i].x * v[i].x + v[i].y * v[i].y + v[i].z * v[i].z + v[i].w * v[i].w;
  }
#pragma unroll
  for (int m = 1; m < 64; m <<= 1) ss += __shfl_xor(ss, m);
  __shared__ float red[4];
  if ((tid & 63) == 0) red[tid >> 6] = ss;
  __syncthreads();
  float tot = red[0] + red[1] + red[2] + red[3];
  float rms = rsqrtf(tot / (float)HID + 1e-5f);
  unsigned short* orow = out + (size_t)row * HID;
#pragma unroll
  for (int i = 0; i < 4; ++i) {
    int base = i * 1024 + tid * 4;
    ushort4 o;
    o.x = f2bf(v[i].x * rms * w[base + 0]);
    o.y = f2bf(v[i].y * rms * w[base + 1]);
    o.z = f2bf(v[i].z * rms * w[base + 2]);
    o.w = f2bf(v[i].w * rms * w[base + 3]);
    *(ushort4*)(orow + base) = o;
  }
}

// ------------------------------------------------- weight transpose+convert
// W[K][N] fp32 -> WT[N][K] bf16. grid (K/64, N/64), 256 threads.
__global__ __launch_bounds__(256) void wtrans_kernel(
    const float* __restrict__ W, unsigned short* __restrict__ WT, int K,
    int N) {
  __shared__ unsigned short t[64][72];
  const int k0 = blockIdx.x * 64, n0 = blockIdx.y * 64;
  const int tid = threadIdx.x;
  const int tk = tid >> 4;            // 0..15
  const int tn4 = (tid & 15) * 4;     // 0..60
#pragma unroll
  for (int p = 0; p < 4; ++p) {
    int k = tk + p * 16;
    float4 v = *(const float4*)(W + (size_t)(k0 + k) * N + n0 + tn4);
    t[tn4 + 0][k] = f2bf(v.x);
    t[tn4 + 1][k] = f2bf(v.y);
    t[tn4 + 2][k] = f2bf(v.z);
    t[tn4 + 3][k] = f2bf(v.w);
  }
  __syncthreads();
#pragma unroll
  for (int p = 0; p < 4; ++p) {
    int n = tk + p * 16;
    ushort4 o = *(const ushort4*)&t[n][tn4];
    *(ushort4*)(WT + (size_t)(n0 + n) * K + k0 + tn4) = o;
  }
}

// ---------------------------------------------------------------- RoPE (in-place, strided)
__global__ __launch_bounds__(256) void rope_kernel(unsigned short* __restrict__ x,
                                                   int nheads, int ld) {
  const int gid = blockIdx.x * 256 + threadIdx.x;
  const int i = gid & 63;
  const int t = gid >> 6;
  const int s = t / nheads;
  const int hh = t - s * nheads;
  float ang = (float)s * exp2f((float)i * (-29.897352853986263f / 64.f));
  float sn, cs;
  sincosf(ang, &sn, &cs);
  size_t base = (size_t)s * ld + hh * DH + i;
  float x1 = bf2f(x[base]);
  float x2 = bf2f(x[base + 64]);
  x[base]      = f2bf(x1 * cs - x2 * sn);
  x[base + 64] = f2bf(x2 * cs + x1 * sn);
}

// ---------------------------------------------------------------- SiLU(g)*u
__global__ __launch_bounds__(256) void silu_mul_kernel(
    const unsigned short* __restrict__ g, const unsigned short* __restrict__ u,
    unsigned short* __restrict__ out) {
  const size_t idx = ((size_t)blockIdx.x * 256 + threadIdx.x) * 4;
  ushort4 gv = *(const ushort4*)(g + idx);
  ushort4 uv = *(const ushort4*)(u + idx);
  float gf[4] = {bf2f(gv.x), bf2f(gv.y), bf2f(gv.z), bf2f(gv.w)};
  float uf[4] = {bf2f(uv.x), bf2f(uv.y), bf2f(uv.z), bf2f(uv.w)};
  ushort4 o;
  unsigned short* op = (unsigned short*)&o;
#pragma unroll
  for (int j = 0; j < 4; ++j) {
    float sl = gf[j] / (1.f + __expf(-gf[j]));
    op[j] = f2bf(sl * uf[j]);
  }
  *(ushort4*)(out + idx) = o;
}

// ---------------------------------------------------------------- GEMM 8-phase
// C[M,N] = A[M,K](bf16,row) @ BT[N,K](bf16,row)^T
// Tile BM x 256, BM = 2*WROWS; BK=64; 512 threads = 8 waves (2M x 4N).
// Double-buffered LDS; counted vmcnt (T3+T4); setprio around MFMA (T5).
template <int WROWS, int EPI>
__global__ __launch_bounds__(512, 2) void gemm8p_kernel(
    const unsigned short* __restrict__ A, const unsigned short* __restrict__ BT,
    void* __restrict__ Cv, const float* __restrict__ res, int gridM, int N,
    int K) {
  constexpr int BM = 2 * WROWS;
  constexpr int MF = WROWS / 32;   // m-frags per quadrant
  constexpr int H  = 2 + BM / 128; // staging halves per K-tile
  constexpr int ABYTES = BM * 128;
  constexpr int BUFBYTES = ABYTES + 32768;
  __shared__ __align__(128) char sm[2 * BUFBYTES];

  const int tid  = threadIdx.x;
  const int lane = tid & 63;
  const int wv   = tid >> 6;
  const int nwg = gridDim.x;
  const int b = blockIdx.x;
  const int logical = (b & 7) * (nwg >> 3) + (b >> 3);
  const int m0 = (logical % gridM) * BM;
  const int n0 = (logical / gridM) * 256;
  const int wm = (wv >> 2) * WROWS;
  const int wn = (wv & 3) * 64;
  const int nt = K >> 6;

  const int srow = tid >> 3;
  const int scolb = (tid & 7) * 16;
  const int sldsbase = wv * 1024;  // HW adds lane*16

  auto stage = [&](int h, int t) {
    const int buf = t & 1;
    const int kt = t * 64;
    char* ldsOp;
    const unsigned short* g;
    int grow0, rowBase;
    if (h < 2) {
      ldsOp = sm + buf * BUFBYTES + ABYTES; g = BT; grow0 = n0; rowBase = h * 128;
    } else {
      ldsOp = sm + buf * BUFBYTES;          g = A;  grow0 = m0; rowBase = (h - 2) * 128;
    }
#pragma unroll
    for (int r = 0; r < 2; ++r) {
      int row = rowBase + r * 64 + srow;
      const char* gp = (const char*)g + ((size_t)(grow0 + row) * K + kt) * 2 +
                       (scolb ^ ((row & 7) << 4));
      gload16(gp, ldsOp + rowBase * 128 + r * 8192 + sldsbase);
    }
  };

  const int kb0 = (lane >> 4) * 16;
  const int lrow = lane & 15;
  auto ldA = [&](const char* sA, int mh, int mf, int ks) {
    int row = wm + mh * (WROWS / 2) + mf * 16 + lrow;
    return *(const bf16x8*)(sA + ((row * 128 + kb0 + ks * 64) ^ ((row & 7) << 4)));
  };
  auto ldB = [&](const char* sB, int j, int ks) {
    int col = wn + (j >> 1) * 32 + (j & 1) * 16 + lrow;
    return *(const bf16x8*)(sB + ((col * 128 + kb0 + ks * 64) ^ ((col & 7) << 4)));
  };

  f32x4 acc[2 * MF][4] = {};

#pragma unroll
  for (int h = 0; h < H; ++h) stage(h, 0);
#pragma unroll
  for (int h = 0; h < H - 1; ++h) stage(h, 1);
  if (H == 4) asm volatile("s_waitcnt vmcnt(6)" ::: "memory");
  else        asm volatile("s_waitcnt vmcnt(4)" ::: "memory");
  __builtin_amdgcn_s_barrier();

  for (int t = 0; t < nt; ++t) {
    const char* sA = sm + (t & 1) * BUFBYTES;
    const char* sB = sA + ABYTES;
    bf16x8 a[MF][2], bb[4][2];

#pragma unroll
    for (int mf = 0; mf < MF; ++mf) {
      a[mf][0] = ldA(sA, 0, mf, 0);
      a[mf][1] = ldA(sA, 0, mf, 1);
    }
#pragma unroll
    for (int j = 0; j < 4; ++j) {
      bb[j][0] = ldB(sB, j, 0);
      bb[j][1] = ldB(sB, j, 1);
    }
    if (t + 1 < nt) stage(H - 1, t + 1);
    __builtin_amdgcn_sched_barrier(0);
    __builtin_amdgcn_s_barrier();
    __builtin_amdgcn_s_setprio(1);
#pragma unroll
    for (int mf = 0; mf < MF; ++mf)
#pragma unroll
      for (int nf = 0; nf < 2; ++nf)
#pragma unroll
        for (int ks = 0; ks < 2; ++ks)
          acc[mf][nf] = __builtin_amdgcn_mfma_f32_16x16x32_bf16(
              a[mf][ks], bb[nf][ks], acc[mf][nf], 0, 0, 0);
    __builtin_amdgcn_s_setprio(0);
    __builtin_amdgcn_sched_barrier(0);
    __builtin_amdgcn_s_barrier();

    if (t + 2 < nt) stage(0, t + 2);
    __builtin_amdgcn_sched_barrier(0);
    __builtin_amdgcn_s_barrier();
    __builtin_amdgcn_s_setprio(1);
#pragma unroll
    for (int mf = 0; mf < MF; ++mf)
#pragma unroll
      for (int nf = 0; nf < 2; ++nf)
#pragma unroll
        for (int ks = 0; ks < 2; ++ks)
          acc[mf][2 + nf] = __builtin_amdgcn_mfma_f32_16x16x32_bf16(
              a[mf][ks], bb[2 + nf][ks], acc[mf][2 + nf], 0, 0, 0);
    __builtin_amdgcn_s_setprio(0);
    __builtin_amdgcn_sched_barrier(0);
    __builtin_amdgcn_s_barrier();

#pragma unroll
    for (int mf = 0; mf < MF; ++mf) {
      a[mf][0] = ldA(sA, 1, mf, 0);
      a[mf][1] = ldA(sA, 1, mf, 1);
    }
    if (t + 2 < nt) stage(1, t + 2);
    __builtin_amdgcn_sched_barrier(0);
    __builtin_amdgcn_s_barrier();
    __builtin_amdgcn_s_setprio(1);
#pragma unroll
    for (int mf = 0; mf < MF; ++mf)
#pragma unroll
      for (int nf = 0; nf < 2; ++nf)
#pragma unroll
        for (int ks = 0; ks < 2; ++ks)
          acc[MF + mf][nf] = __builtin_amdgcn_mfma_f32_16x16x32_bf16(
              a[mf][ks], bb[nf][ks], acc[MF + mf][nf], 0, 0, 0);
    __builtin_amdgcn_s_setprio(0);
    __builtin_amdgcn_sched_barrier(0);
    __builtin_amdgcn_s_barrier();

    if (H == 4 && t + 2 < nt) stage(2, t + 2);
    if (t + 2 < nt) {
      if (H == 4) asm volatile("s_waitcnt vmcnt(6)" ::: "memory");
      else        asm volatile("s_waitcnt vmcnt(4)" ::: "memory");
    } else {
      asm volatile("s_waitcnt vmcnt(0)" ::: "memory");
    }
    __builtin_amdgcn_sched_barrier(0);
    __builtin_amdgcn_s_barrier();
    __builtin_amdgcn_s_setprio(1);
#pragma unroll
    for (int mf = 0; mf < MF; ++mf)
#pragma unroll
      for (int nf = 0; nf < 2; ++nf)
#pragma unroll
        for (int ks = 0; ks < 2; ++ks)
          acc[MF + mf][2 + nf] = __builtin_amdgcn_mfma_f32_16x16x32_bf16(
              a[mf][ks], bb[2 + nf][ks], acc[MF + mf][2 + nf], 0, 0, 0);
    __builtin_amdgcn_s_setprio(0);
    __builtin_amdgcn_sched_barrier(0);
    __builtin_amdgcn_s_barrier();
  }

  const int rb = (lane >> 4) * 4;
#pragma unroll
  for (int i = 0; i < 2 * MF; ++i) {
    const int mh = i / MF, mf = i % MF;
#pragma unroll
    for (int j = 0; j < 4; ++j) {
#pragma unroll
      for (int r = 0; r < 4; ++r) {
        size_t row = (size_t)(m0 + wm + mh * (WROWS / 2) + mf * 16 + rb + r);
        size_t col = (size_t)(n0 + wn + (j >> 1) * 32 + (j & 1) * 16 + lrow);
        float vv = acc[i][j][r];
        if (EPI == 0) {
          ((unsigned short*)Cv)[row * N + col] = f2bf(vv);
        } else {
          ((float*)Cv)[row * N + col] = vv + res[row * N + col];
        }
      }
    }
  }
}

// ---------------------------------------------------------------- Flash attention
// grid 512 x 512 threads. Block = 128 q-rows x 1 head, 8 waves x 16 rows.
// K/V double-buffered; 1 barrier/tile; prefetch t+1 under compute of t.
// Blocks ordered longest-first (LPT over causal tile counts).
__global__ __launch_bounds__(512, 1) void attn_kernel(
    const unsigned short* __restrict__ QKV, unsigned short* __restrict__ Ob) {
  // LDS: Q 32K | K0 16K | K1 16K | V0 16K | V1 16K | P 16K  = 112K
  __shared__ __align__(128) char sm[114688];
  char* sQ  = sm;
  char* sK0 = sm + 32768;
  char* sK1 = sm + 49152;
  char* sV0 = sm + 65536;
  char* sV1 = sm + 81920;
  char* sP  = sm + 98304;
  const int tid  = threadIdx.x;
  const int lane = tid & 63;
  const int wv   = tid >> 6;
  // LPT: descending work order. logical 0..511 -> xr 15..0, 32 heads each.
  const int logical = blockIdx.x;
  const int xr = 15 - (logical >> 5);
  const int h = logical & 31;
  const int qb0 = xr * 128;
  const int hkv = h >> 2;  // G = 4
  const int rbase = (lane >> 4) * 4;
  const int cbase = lane & 15;
  const unsigned short* Qp = QKV + h * DH;
  const unsigned short* Kp = QKV + NH * DH + hkv * DH;
  const unsigned short* Vp = QKV + NH * DH + NKV * DH + hkv * DH;

  // ---- stage Q (128 x 256B), swizzle (row&15)<<4
#pragma unroll
  for (int i = 0; i < 4; ++i) {
    int offs = i * 8192 + tid * 16;
    int row = offs >> 8, col = offs & 255;
    const char* gp = (const char*)Qp + ((size_t)(qb0 + row) * QKVN) * 2 +
                     (col ^ ((row & 15) << 4));
    gload16(gp, sQ + i * 8192 + wv * 1024);
  }

  auto stageK = [&](int t) {
    char* dst = (t & 1) ? sK1 : sK0;
    const int kt0 = t * 64;
#pragma unroll
    for (int i = 0; i < 2; ++i) {
      int offs = i * 8192 + tid * 16;
      int row = offs >> 8, col = offs & 255;
      const char* gp = (const char*)Kp + ((size_t)(kt0 + row) * QKVN) * 2 +
                       (col ^ ((row & 15) << 4));
      gload16(gp, dst + i * 8192 + wv * 1024);
    }
  };

  // V stage: thread covers rows kv4..kv4+3 at cols d4..d4+3.
  const int d4  = (tid & 31) * 4;
  const int kv4 = (tid >> 5) * 4;
  const int rot = (tid >> 1) & 3;
  auto loadV = [&](int t, ushort4* vr) {
    const unsigned short* g0 = Vp + (size_t)(t * 64 + kv4) * QKVN + d4;
#pragma unroll
    for (int k = 0; k < 4; ++k) vr[k] = *(const ushort4*)(g0 + (size_t)k * QKVN);
  };
  auto writeV = [&](int t, const ushort4* vr) {
    char* dst = (t & 1) ? sV1 : sV0;
    const unsigned short* a0 = (const unsigned short*)&vr[0];
    const unsigned short* a1 = (const unsigned short*)&vr[1];
    const unsigned short* a2 = (const unsigned short*)&vr[2];
    const unsigned short* a3 = (const unsigned short*)&vr[3];
#pragma unroll
    for (int j = 0; j < 4; ++j) {
      int jj = (j + rot) & 3;
      int dd = d4 + jj;
      uint2 pk;
      pk.x = (unsigned)a0[jj] | ((unsigned)a1[jj] << 16);
      pk.y = (unsigned)a2[jj] | ((unsigned)a3[jj] << 16);
      *(uint2*)(dst + ((dd * 128 + kv4 * 2) ^ ((dd & 7) << 4))) = pk;
    }
  };

  // ---- prologue: tile 0
  ushort4 vr[4];
  stageK(0);
  loadV(0, vr);
  asm volatile("s_waitcnt vmcnt(0)" ::: "memory");
  writeV(0, vr);
  __syncthreads();

  // ---- hoist Q fragments (wave rows wv*16 .. +15)
  const int qrow = wv * 16 + (lane & 15);
  bf16x8 aq[4];
#pragma unroll
  for (int kk = 0; kk < 4; ++kk) {
    int kb = (lane >> 4) * 16 + kk * 64;
    aq[kk] = *(const bf16x8*)(sQ + ((qrow * 256 + kb) ^ ((qrow & 15) << 4)));
  }

  f32x4 oacc[8] = {};
  float m_r[4] = {-1e30f, -1e30f, -1e30f, -1e30f};
  float l_r[4] = {0.f, 0.f, 0.f, 0.f};
  const int ntiles = 2 * (xr + 1);

  for (int t = 0; t < ntiles; ++t) {
    const int kt0 = t * 64;
    const char* cK = (t & 1) ? sK1 : sK0;
    const char* cV = (t & 1) ? sV1 : sV0;
    if (t + 1 < ntiles) {
      stageK(t + 1);
      loadV(t + 1, vr);
    }

    // ---- S = Q K^T (wave: 16 q x 64 kv)
    f32x4 sacc[4] = {};
#pragma unroll
    for (int kk = 0; kk < 4; ++kk) {
      int kb = (lane >> 4) * 16 + kk * 64;
#pragma unroll
      for (int ni = 0; ni < 4; ++ni) {
        int krow = ni * 16 + (lane & 15);
        bf16x8 bk =
            *(const bf16x8*)(cK + ((krow * 256 + kb) ^ ((krow & 15) << 4)));
        sacc[ni] = __builtin_amdgcn_mfma_f32_16x16x32_bf16(aq[kk], bk,
                                                           sacc[ni], 0, 0, 0);
      }
    }

    // ---- online softmax
    const float scale = 0.08838834764831845f;  // 1/sqrt(128)
#pragma unroll
    for (int r = 0; r < 4; ++r) {
      int qg = qb0 + wv * 16 + rbase + r;
      float mx = -1e30f;
#pragma unroll
      for (int ni = 0; ni < 4; ++ni) {
        int cg = kt0 + ni * 16 + cbase;
        float sv = sacc[ni][r] * scale;
        sv = (cg <= qg) ? sv : -1e30f;
        sacc[ni][r] = sv;
        mx = fmaxf(mx, sv);
      }
      mx = fmaxf(mx, __shfl_xor(mx, 1));
      mx = fmaxf(mx, __shfl_xor(mx, 2));
      mx = fmaxf(mx, __shfl_xor(mx, 4));
      mx = fmaxf(mx, __shfl_xor(mx, 8));
      float mnew = fmaxf(m_r[r], mx);
      float sf = __expf(m_r[r] - mnew);
      m_r[r] = mnew;
      float rsum = 0.f;
#pragma unroll
      for (int ni = 0; ni < 4; ++ni) {
        float pv = __expf(sacc[ni][r] - mnew);
        sacc[ni][r] = pv;
        rsum += pv;
      }
      rsum += __shfl_xor(rsum, 1);
      rsum += __shfl_xor(rsum, 2);
      rsum += __shfl_xor(rsum, 4);
      rsum += __shfl_xor(rsum, 8);
      l_r[r] = l_r[r] * sf + rsum;
#pragma unroll
      for (int nt2 = 0; nt2 < 8; ++nt2) oacc[nt2][r] *= sf;
    }

    // ---- P -> LDS (per-wave [16][64] bf16), then PV
    char* pw = sP + wv * 2048;
#pragma unroll
    for (int ni = 0; ni < 4; ++ni)
#pragma unroll
      for (int r = 0; r < 4; ++r) {
        int row = rbase + r;
        int cb2 = (ni * 16 + cbase) * 2;
        *(unsigned short*)(pw + ((row * 128 + cb2) ^ ((row & 7) << 4))) =
            f2bf(sacc[ni][r]);
      }
    asm volatile("s_waitcnt lgkmcnt(0)" ::: "memory");

#pragma unroll
    for (int kk = 0; kk < 2; ++kk) {
      int kb = (lane >> 4) * 16 + kk * 64;
      int prow = lane & 15;
      bf16x8 ap =
          *(const bf16x8*)(pw + ((prow * 128 + kb) ^ ((prow & 7) << 4)));
#pragma unroll
      for (int nt2 = 0; nt2 < 8; ++nt2) {
        int vrow = nt2 * 16 + (lane & 15);
        bf16x8 bv =
            *(const bf16x8*)(cV + ((vrow * 128 + kb) ^ ((vrow & 7) << 4)));
        oacc[nt2] =
            __builtin_amdgcn_mfma_f32_16x16x32_bf16(ap, bv, oacc[nt2], 0, 0, 0);
      }
    }

    // ---- land next tile's V; barrier publishes K(t+1), V(t+1)
    if (t + 1 < ntiles) {
      asm volatile("s_waitcnt vmcnt(0)" ::: "memory");
      writeV(t + 1, vr);
    }
    __syncthreads();
  }

  // ---- epilogue: O / l
#pragma unroll
  for (int nt2 = 0; nt2 < 8; ++nt2)
#pragma unroll
    for (int r = 0; r < 4; ++r) {
      size_t row = (size_t)(qb0 + wv * 16 + rbase + r);
      int col = nt2 * 16 + cbase;
      Ob[row * (NH * DH) + h * DH + col] = f2bf(oacc[nt2][r] / l_r[r]);
    }
}

// ---------------------------------------------------------------- host
extern "C" void kernel_launch(void* const* d_in, const int* in_sizes, int n_in,
                              void* d_out, int out_size, void* d_ws,
                              size_t ws_size, hipStream_t stream) {
  const float* hs  = (const float*)d_in[0];
  const float* wq  = (const float*)d_in[1];
  const float* wk  = (const float*)d_in[2];
  const float* wvp = (const float*)d_in[3];
  const float* wo  = (const float*)d_in[4];
  const float* wg  = (const float*)d_in[5];
  const float* wu  = (const float*)d_in[6];
  const float* wd  = (const float*)d_in[7];
  const float* ln1 = (const float*)d_in[8];
  const float* ln2 = (const float*)d_in[9];

  char* p = (char*)d_ws;
  size_t need = 0;
  auto alloc = [&](size_t bytes) {
    char* r = p + need;
    need += (bytes + 255) & ~(size_t)255;
    return r;
  };
  unsigned short* T1   = (unsigned short*)alloc((size_t)FF * HID * 2);  // 117MB
  unsigned short* xn   = (unsigned short*)alloc((size_t)SEQ * HID * 2);
  unsigned short* qkv  = (unsigned short*)alloc((size_t)SEQ * QKVN * 2);
  unsigned short* ab   = (unsigned short*)alloc((size_t)SEQ * NH * DH * 2);
  float*          h2   = (float*)alloc((size_t)SEQ * HID * 4);
  unsigned short* xn2  = (unsigned short*)alloc((size_t)SEQ * HID * 2);
  unsigned short* gbuf = (unsigned short*)alloc((size_t)SEQ * FF * 2);
  unsigned short* ubuf = (unsigned short*)alloc((size_t)SEQ * FF * 2);
  if (need > ws_size) return;  // workspace too small: fail visibly

  // 1) rmsnorm1
  rmsnorm_kernel<<<SEQ, 256, 0, stream>>>(hs, ln1, xn);
  // 2) transpose wq|wk|wv into T1 -> [QKVN][HID] bf16
  wtrans_kernel<<<dim3(HID / 64, HID / 64), 256, 0, stream>>>(wq, T1, HID, HID);
  wtrans_kernel<<<dim3(HID / 64, (NKV * DH) / 64), 256, 0, stream>>>(
      wk, T1 + (size_t)(NH * DH) * HID, HID, NKV * DH);
  wtrans_kernel<<<dim3(HID / 64, (NKV * DH) / 64), 256, 0, stream>>>(
      wvp, T1 + (size_t)(NH * DH + NKV * DH) * HID, HID, NKV * DH);
  // 3) fused qkv projection (grid 8*24=192)
  gemm8p_kernel<128, 0><<<(SEQ / 256) * (QKVN / 256), 512, 0, stream>>>(
      xn, T1, qkv, nullptr, SEQ / 256, QKVN, HID);
  // 4) RoPE (in place on q and k slices)
  rope_kernel<<<(SEQ * NH * 64) / 256, 256, 0, stream>>>(qkv, NH, QKVN);
  rope_kernel<<<(SEQ * NKV * 64) / 256, 256, 0, stream>>>(qkv + NH * DH, NKV,
                                                          QKVN);
  // 5) attention (512 blocks, LPT order)
  attn_kernel<<<512, 512, 0, stream>>>(qkv, ab);
  // 6) o-proj + residual -> h2 (fp32); BM=128 -> grid 16*16=256 (full chip)
  wtrans_kernel<<<dim3(HID / 64, HID / 64), 256, 0, stream>>>(wo, T1, HID, HID);
  gemm8p_kernel<64, 1><<<(SEQ / 128) * (HID / 256), 512, 0, stream>>>(
      ab, T1, h2, hs, SEQ / 128, HID, HID);
  // 7) rmsnorm2
  rmsnorm_kernel<<<SEQ, 256, 0, stream>>>(h2, ln2, xn2);
  // 8) gate (grid 8*56=448)
  wtrans_kernel<<<dim3(HID / 64, FF / 64), 256, 0, stream>>>(wg, T1, HID, FF);
  gemm8p_kernel<128, 0><<<(SEQ / 256) * (FF / 256), 512, 0, stream>>>(
      xn2, T1, gbuf, nullptr, SEQ / 256, FF, HID);
  // 9) up
  wtrans_kernel<<<dim3(HID / 64, FF / 64), 256, 0, stream>>>(wu, T1, HID, FF);
  gemm8p_kernel<128, 0><<<(SEQ / 256) * (FF / 256), 512, 0, stream>>>(
      xn2, T1, ubuf, nullptr, SEQ / 256, FF, HID);
  // 10) silu(g)*u -> gbuf (in place)
  silu_mul_kernel<<<((size_t)SEQ * FF) / 1024, 256, 0, stream>>>(gbuf, ubuf,
                                                                 gbuf);
  // 11) down-proj + residual -> out (fp32); BM=128 -> grid 256
  wtrans_kernel<<<dim3(FF / 64, HID / 64), 256, 0, stream>>>(wd, T1, FF, HID);
  gemm8p_kernel<64, 1><<<(SEQ / 128) * (HID / 256), 512, 0, stream>>>(
      gbuf, T1, d_out, h2, SEQ / 128, HID, FF);
}